// Round 7
// baseline (102.774 us; speedup 1.0000x reference)
//
#include <hip/hip_runtime.h>
#include <math.h>

// Problem constants
#define BATCH 32
#define H 512
#define W 512
#define OUT_HW 502           // 512 - 11 + 1
#define TS_X 64              // R24: output strip width 32 -> 64 (halo 1.5x -> 1.25x)
#define BAND 32              // output rows per band
#define NBANDS 16            // full image height per block
#define NTX 8
#define NBLOCKS (NTX * BATCH)    // 256 -> one round at 1 block/CU (512 thr, 8 waves)
#define N1 ((double)BATCH * H * W)
#define N2 ((double)BATCH * OUT_HW * OUT_HW)

// LDS row strides, in halves.
// raw stride 88 (176 B = 44 dw -> 12 banks*nn, gcd(12,32)=4 -> period 8,
// 2 lanes/bank = free, m136); 16B-aligned. rbt stride 56 as R19 (28 banks*nn,
// period 8, free).
#define RSTR 88
#define TSTR 56
#define RING 48

struct GaussW { float g[11]; };

typedef _Float16 h8  __attribute__((ext_vector_type(8)));
typedef __fp16   h2t __attribute__((ext_vector_type(2)));   // cvt_pkrtz result type
typedef float    f4t __attribute__((ext_vector_type(4)));

// History (do not re-break):
//   (256,3)/(256,4) launch bounds: catastrophic spill. Keep 2 waves/SIMD cap.
// R13..R16: both 11-tap blurs as banded-Toeplitz MFMA (mfma_f32_16x16x32_f16),
// shared G-fragment B[k][n]=g[k-n]; raw ring (mod 48); rbt transposed
// [col][slot]. R14 NaN lesson: zero-weight MFMA taps still propagate NaN --
// every MFMA-read LDS location must be written or zeroed (stale FINITE ok on
// zero-weight taps). R16: fp16-packed prep. R17: pipelined global loads.
// R18 (tall strips + XCD decode) NEUTRAL. R19 (bank pads) NEUTRAL.
// R20 WIN -5.6us (h-blur unroll + fewer barriers + slim finalize).
// R21 (work removal) REGRESS. R22 (lgkmcnt barrier) REGRESS.
// R23 (1 phase/band) NEUTRAL == R20.
// Conclusion: post-R20 kernel sits at the HBM floor of its fetch volume
// (~100.7 MB @ ~6.1 TB/s ~= 16.5us). R24 attacks fetch volume: TS_X=64
// halves the column halo -> 84.4 MB. 512-thr blocks, 1 block/CU, same
// R20 2-phase/ring-48 schedule; per-wave MFMA counts unchanged.
__global__ __launch_bounds__(512, 2)
void ssim_mfma_kernel(const float* __restrict__ pred,
                      const float* __restrict__ targ,
                      float* __restrict__ ws_contrib,
                      GaussW gw)
{
    __shared__ __align__(16) _Float16 raw[4][RING * RSTR];  // [ch][slot*RSTR + px], 33.8 KB
    __shared__ __align__(16) _Float16 rbt[4][TS_X * TSTR];  // [ch][col*TSTR + slot], 28.7 KB
    __shared__ float red[16];

    const int tid = threadIdx.x;
    // XCD-binding decode: xcd = bid&7 owns images 4*xcd..4*xcd+3, all 8 tx.
    // Bijective: 256 = 8 xcd * (8 tx * 4 img-slot).
    const int bid = blockIdx.x;
    const int tx  = bid >> 5;                     // 0..7
    const int b   = ((bid & 7) << 2) | ((bid >> 3) & 3);
    const int ox0 = tx * TS_X;
    const int cols = min(TS_X, OUT_HW - ox0);     // 64, or 54 for tx=7
    const bool interior_x = (ox0 + 80 <= W);      // full 80-px window in-bounds (tx<=6)

    const float* __restrict__ pb = pred + ((size_t)b << 18);
    const float* __restrict__ tb = targ + ((size_t)b << 18);

    const int lane = tid & 63, wave = tid >> 6;   // 8 waves
    const int quad = lane >> 4, nn = lane & 15, quad8 = quad << 3;

    // Per-thread prep item geometry: row pr, 8-px group pg (10 groups = 80 px)
    const int pr = tid / 10, pg = tid - pr * 10;
    const bool pactive = interior_x | (pg < 8);   // tx=7: pg 8,9 would read OOB

    // ---- Zero-fill raw (NaN defense: band-0 ring slots 42-47 and tx=7's
    // px 64-79 are MFMA-read but never written; recycled slots stay finite).
    // rbt needs no fill: h-blur writes every slot/col the v-blur reads.
    {
        _Float16* base = &raw[0][0];
        const int total = 4 * RING * RSTR;
        for (int i = tid * 8; i < total; i += 512 * 8)
            *(f4t*)(base + i) = f4t{0.f, 0.f, 0.f, 0.f};
    }

    // ---- Constant Toeplitz G fragment: B[k=quad8+j][n=nn] = g[k-n] (0 outside)
    h8 gfrag;
    #pragma unroll
    for (int j = 0; j < 8; ++j) {
        const int kk = quad8 + j - nn;
        float val = 0.f;
        #pragma unroll
        for (int t2 = 0; t2 < 11; ++t2) val = (kk == t2) ? gw.g[t2] : val;
        gfrag[j] = (_Float16)val;
    }
    const f4t zero4 = {0.f, 0.f, 0.f, 0.f};
    const float C1 = 1e-4f, C2 = 9e-4f;

    float mse_local = 0.f, ssim_local = 0.f;

    // V-blur + SSIM epilogue for the band whose output rows start at out0v.
    // 8 out-tiles (4 coltiles x 2 rowtiles), one per wave, 4 ch MFMAs each.
    auto do_vblur = [&](int out0v) {
        const int c0 = (wave & 3) << 4, r0v = (wave >> 2) << 4;
        f4t dv2[4];
        #pragma unroll
        for (int ch = 0; ch < 4; ++ch) {
            const h8 a = *(const h8*)&rbt[ch][(c0 + nn) * TSTR + r0v + quad8];
            dv2[ch] = __builtin_amdgcn_mfma_f32_16x16x32_f16(a, gfrag, zero4, 0, 0, 0);
        }
        // D[row=quad*4+reg][col=nn]: out row = out0v+r0v+nn, out px col = c0+quad*4+reg
        const int rowg = out0v + r0v + nn;
        if (rowg < OUT_HW) {
            #pragma unroll
            for (int reg = 0; reg < 4; ++reg) {
                const int cl = c0 + (quad << 2) + reg;
                if (cl < cols) {
                    const float A = dv2[0][reg], Bv = dv2[1][reg];
                    const float U = dv2[2][reg], V  = dv2[3][reg];
                    const float A2 = A * A, B2 = Bv * Bv;
                    const float mu12_2 = 0.5f * (A2 - B2);   // 2*mu1*mu2
                    const float musq   = 0.5f * (A2 + B2);   // mu1^2+mu2^2
                    const float sig12_2 = 0.5f * (U - V) - mu12_2;
                    const float sigsum  = 0.5f * (U + V) - musq;
                    const float num = (mu12_2 + C1) * (sig12_2 + C2);
                    const float den = (musq + C1) * (sigsum + C2) + 1e-6f;
                    ssim_local += num * __builtin_amdgcn_rcpf(den);
                }
            }
        }
    };

    // ---- Prefetch band 0's global data into registers (rows 0..41, 420 items)
    f4t pf0, pf1, pf2, pf3;
    {
        if ((tid < 42 * 10) & pactive) {
            const int base = (pr << 9) + ox0 + 8 * pg;
            pf0 = *(const f4t*)(pb + base);
            pf1 = *(const f4t*)(pb + base + 4);
            pf2 = *(const f4t*)(tb + base);
            pf3 = *(const f4t*)(tb + base + 4);
        }
    }

    __syncthreads();   // zeros visible before h-blur reads

    // Ring bases (uniform scalars, carried mod 48):
    //   hbase = slot of first NEW row this band, obase = slot of ring row out0
    int hbase = 0, obase = 0;

    // Per band (R20 schedule): phase1 { vblur(band-1) | prep(band) |
    // prefetch(band+1) }, barrier, phase2 { hblur(band) }, barrier.
    // Ordering audit identical to R20 (row/slot arithmetic unchanged).
    #pragma unroll 1
    for (int band = 0; band < NBANDS; ++band) {
        const int out0 = band * BAND;
        const int h0   = (band == 0) ? 0 : (out0 + 10);   // first NEW raw row
        const int nnew = min(out0 + 42, H) - h0;          // 42 / 32 / 22 (last)

        // ---- Phase 1a: v-blur + SSIM epilogue for the PREVIOUS band
        if (band > 0) do_vblur(out0 - BAND);

        // ---- Phase 1b: consume prefetched registers: fp16-packed prep -> raw
        if ((tid < nnew * 10) & pactive) {
            const h2t hp0 = __builtin_amdgcn_cvt_pkrtz(pf0[0], pf0[1]);
            const h2t hp1 = __builtin_amdgcn_cvt_pkrtz(pf0[2], pf0[3]);
            const h2t hp2 = __builtin_amdgcn_cvt_pkrtz(pf1[0], pf1[1]);
            const h2t hp3 = __builtin_amdgcn_cvt_pkrtz(pf1[2], pf1[3]);
            const h2t ht0 = __builtin_amdgcn_cvt_pkrtz(pf2[0], pf2[1]);
            const h2t ht1 = __builtin_amdgcn_cvt_pkrtz(pf2[2], pf2[3]);
            const h2t ht2 = __builtin_amdgcn_cvt_pkrtz(pf3[0], pf3[1]);
            const h2t ht3 = __builtin_amdgcn_cvt_pkrtz(pf3[2], pf3[3]);
            __align__(16) h2t sv[4], dv[4], ssv[4], ddv[4];
            sv[0] = hp0 + ht0; sv[1] = hp1 + ht1; sv[2] = hp2 + ht2; sv[3] = hp3 + ht3;
            dv[0] = hp0 - ht0; dv[1] = hp1 - ht1; dv[2] = hp2 - ht2; dv[3] = hp3 - ht3;
            ssv[0] = sv[0] * sv[0]; ssv[1] = sv[1] * sv[1];
            ssv[2] = sv[2] * sv[2]; ssv[3] = sv[3] * sv[3];
            ddv[0] = dv[0] * dv[0]; ddv[1] = dv[1] * dv[1];
            ddv[2] = dv[2] * dv[2]; ddv[3] = dv[3] * dv[3];

            // MSE: every loaded row owned exactly once; owned cols = groups 0-7
            // (px ox0..ox0+63).
            if (pg < 8) {
                const h2t macc = (ddv[0] + ddv[1]) + (ddv[2] + ddv[3]);
                mse_local += (float)macc[0] + (float)macc[1];
            }

            int s = hbase + pr;                   // <= 47+41 < 96
            s -= (s >= RING) ? RING : 0;
            const int off = s * RSTR + 8 * pg;
            *(f4t*)&raw[0][off] = *(const f4t*)sv;
            *(f4t*)&raw[1][off] = *(const f4t*)dv;
            *(f4t*)&raw[2][off] = *(const f4t*)ssv;
            *(f4t*)&raw[3][off] = *(const f4t*)ddv;
        }

        // ---- Phase 1c: prefetch band+1's global data (overlaps h-blur below)
        if (band + 1 < NBANDS) {
            const int nh0   = out0 + BAND + 10;
            const int nnnew = min(out0 + BAND + 42, H) - nh0;
            if ((tid < nnnew * 10) & pactive) {
                const int base = ((nh0 + pr) << 9) + ox0 + 8 * pg;
                pf0 = *(const f4t*)(pb + base);
                pf1 = *(const f4t*)(pb + base + 4);
                pf2 = *(const f4t*)(tb + base);
                pf3 = *(const f4t*)(tb + base + 4);
            }
        }
        __syncthreads();   // raw ready; vblur(band-1) rbt reads complete

        // ---- Phase 2: h-blur via MFMA. 48 tiles (3 rowtiles x 4 coltiles x
        // 4 ch) / 8 waves = 6 compile-time tiles per wave, fully unrolled
        // (R20). ch = wave&3; coltile-pair = wave>>2 (j0 base 0 or 32).
        {
            const int ch = wave & 3, jb = (wave >> 2) << 5;
            #pragma unroll
            for (int k = 0; k < 6; ++k) {
                const int j0 = jb + ((k & 1) << 4), r0 = (k >> 1) << 4;
                int u = obase + r0 + nn;          // <= 47+32+15 < 96
                u -= (u >= RING) ? RING : 0;
                const h8 a = *(const h8*)&raw[ch][u * RSTR + j0 + quad8];
                const f4t dacc = __builtin_amdgcn_mfma_f32_16x16x32_f16(a, gfrag, zero4, 0, 0, 0);
                // D[row=quad*4+reg][col=nn]: out col = j0+nn, slot = r0+quad*4+reg
                h2t* wp = (h2t*)&rbt[ch][(j0 + nn) * TSTR + r0 + (quad << 2)];
                wp[0] = __builtin_amdgcn_cvt_pkrtz(dacc[0], dacc[1]);
                wp[1] = __builtin_amdgcn_cvt_pkrtz(dacc[2], dacc[3]);
            }
        }
        __syncthreads();   // rbt ready for vblur(band) in next phase1

        hbase += nnew;  hbase -= (hbase >= RING) ? RING : 0;
        obase += BAND;  obase -= (obase >= RING) ? RING : 0;
    }

    // ---- Last band's v-blur (no following band to merge it into)
    do_vblur((NBANDS - 1) * BAND);

    // ---- Block reduction (512 threads = 8 waves)
    #pragma unroll
    for (int off = 32; off > 0; off >>= 1) {
        ssim_local += __shfl_down(ssim_local, off, 64);
        mse_local  += __shfl_down(mse_local,  off, 64);
    }
    if ((tid & 63) == 0) { red[wave] = ssim_local; red[8 + wave] = mse_local; }
    __syncthreads();
    if (tid == 0) {
        float s = 0.f, m = 0.f;
        #pragma unroll
        for (int i = 0; i < 8; ++i) { s += red[i]; m += red[8 + i]; }
        const double contrib = 0.6 * (double)m / N1 - 0.4 * (double)s / N2;
        ws_contrib[bid] = (float)contrib;
    }
}

// R20: barrier-free single-wave finalize.
__global__ __launch_bounds__(64)
void finalize_kernel(const float* __restrict__ ws_contrib,
                     float* __restrict__ out)
{
    const int tid = threadIdx.x;
    double s = 0.0;
    #pragma unroll
    for (int i = 0; i < NBLOCKS / 64; ++i)
        s += (double)ws_contrib[tid + i * 64];
    #pragma unroll
    for (int off = 32; off > 0; off >>= 1)
        s += __shfl_down(s, off, 64);
    if (tid == 0)
        out[0] = (float)(0.4 + s);
}

extern "C" void kernel_launch(void* const* d_in, const int* in_sizes, int n_in,
                              void* d_out, int out_size, void* d_ws, size_t ws_size,
                              hipStream_t stream)
{
    const float* pred = (const float*)d_in[0];
    const float* targ = (const float*)d_in[1];
    float* out = (float*)d_out;
    float* ws_contrib = (float*)d_ws;

    // Gaussian taps: computed host-side in double, normalized, passed by value.
    GaussW gw;
    double g[11], sum = 0.0;
    for (int i = 0; i < 11; ++i) { double x = i - 5.0; g[i] = exp(-x * x / 4.5); sum += g[i]; }
    for (int i = 0; i < 11; ++i) gw.g[i] = (float)(g[i] / sum);

    ssim_mfma_kernel<<<dim3(NBLOCKS), 512, 0, stream>>>(pred, targ, ws_contrib, gw);
    finalize_kernel<<<1, 64, 0, stream>>>(ws_contrib, out);
}